// Round 14
// baseline (296.917 us; speedup 1.0000x reference)
//
#include <hip/hip_runtime.h>
#include <math.h>

// Problem constants (reference: B=2, N=512, D=64)
#define BB 2
#define NN2 512
#define EPS 1e-5f
#define NT 64      // 512/8 pair-tiles per dim
#define TP 2080    // NT*(NT+1)/2 upper-triangular tile pairs

// ---------------- workspace layout (float offsets) ----------------
#define OFF_W2T    0        // [128][64]  s2-folded W2 transposed -> [k][o]
#define OFF_C2     8192     // [64]
#define OFF_W3T    8256     // [64][32]   s3-folded W3 transposed -> [k][o]
#define OFF_C3     10304    // [32]
#define OFF_NVALID 10336    // [B] ints (16-float pad)
#define OFF_U      10352    // [B*N][128]
#define OFF_V      141424   // [B*N][128]
#define OFF_NF     272496   // [B*N][64]

// ---------------- P1: everything precomputable, one kernel ----------------
// blocks 0..127: U/V/nf for 8 nodes each (W1 fold inlined - no cross-block dep)
// blocks 128..135: W2t fold; block 136: W3t fold; block 137: c2/c3/nvalid
__global__ __launch_bounds__(256) void prep_all(
    const float* __restrict__ feat, const int* __restrict__ masks,
    const float* __restrict__ W1, const float* __restrict__ b1,
    const float* __restrict__ W2, const float* __restrict__ b2,
    const float* __restrict__ W3, const float* __restrict__ b3,
    const float* __restrict__ g1, const float* __restrict__ be1,
    const float* __restrict__ m1, const float* __restrict__ v1,
    const float* __restrict__ g2, const float* __restrict__ be2,
    const float* __restrict__ m2, const float* __restrict__ v2,
    const float* __restrict__ g3, const float* __restrict__ be3,
    const float* __restrict__ m3, const float* __restrict__ v3,
    float* __restrict__ ws, int* __restrict__ nvalid)
{
    const int blk = blockIdx.x, t = threadIdx.x;
    if (blk < 128) {
        __shared__ float F[8][64];
        const int nb = blk * 8;
        if (t < 128) {
            int r = t >> 4, c = (t & 15) * 4;
            *(float4*)&F[r][c] = *(const float4*)&feat[(nb + r) * 64 + c];
        }
        __syncthreads();
        // normalized features: 16 lanes per node, 8 nodes by threads 0..127
        if (t < 128) {
            int g = t >> 4, c0 = t & 15;
            float x0 = F[g][c0],      x1 = F[g][c0 + 16];
            float x2 = F[g][c0 + 32], x3 = F[g][c0 + 48];
            float ss = x0*x0 + x1*x1 + x2*x2 + x3*x3;
            ss += __shfl_xor(ss, 1);
            ss += __shfl_xor(ss, 2);
            ss += __shfl_xor(ss, 4);
            ss += __shfl_xor(ss, 8);
            float inv = 1.0f / fmaxf(sqrtf(ss), 1e-12f);
            float* nfp = ws + OFF_NF + (size_t)(nb + g) * 64 + c0;
            nfp[0]  = x0 * inv; nfp[16] = x1 * inv;
            nfp[32] = x2 * inv; nfp[48] = x3 * inv;
        }
        // U/V: half g = t>>7 handles nodes nb+4g..+3; lane o = t&127 = channel
        const int g = t >> 7, o = t & 127;
        const float s1 = g1[o] * rsqrtf(v1[o] + EPS);
        const float vb = s1 * b1[o] + be1[o] - m1[o] * s1;
        float aU[4] = {0.f,0.f,0.f,0.f}, aV[4] = {0.f,0.f,0.f,0.f};
        const float* w1r = &W1[o * 128];
        #pragma unroll 4
        for (int dq = 0; dq < 16; dq++) {
            float4 wa = *(const float4*)&w1r[dq * 4];
            float4 wb = *(const float4*)&w1r[64 + dq * 4];
            #pragma unroll
            for (int n = 0; n < 4; n++) {
                float4 fv = *(const float4*)&F[g * 4 + n][dq * 4];
                aU[n] = fmaf(fv.x, wa.x, aU[n]); aV[n] = fmaf(fv.x, wb.x, aV[n]);
                aU[n] = fmaf(fv.y, wa.y, aU[n]); aV[n] = fmaf(fv.y, wb.y, aV[n]);
                aU[n] = fmaf(fv.z, wa.z, aU[n]); aV[n] = fmaf(fv.z, wb.z, aV[n]);
                aU[n] = fmaf(fv.w, wa.w, aU[n]); aV[n] = fmaf(fv.w, wb.w, aV[n]);
            }
        }
        float* Up = ws + OFF_U;
        float* Vp = ws + OFF_V;
        #pragma unroll
        for (int n = 0; n < 4; n++) {
            Up[(size_t)(nb + g * 4 + n) * 128 + o] = aU[n] * s1;
            Vp[(size_t)(nb + g * 4 + n) * 128 + o] = aV[n] * s1 + vb;
        }
    } else if (blk < 136) {
        // W2t[k][o] = W2[o][k] * s2[o]
        int e0 = (blk - 128) * 1024 + t * 4;
        #pragma unroll
        for (int q = 0; q < 4; q++) {
            int e = e0 + q;
            int o = e & 63, k = e >> 6;
            float s = g2[o] * rsqrtf(v2[o] + EPS);
            ws[OFF_W2T + e] = W2[o * 128 + k] * s;
        }
    } else if (blk == 136) {
        // W3t[k][o] = W3[o][k] * s3[o]
        #pragma unroll
        for (int q = 0; q < 8; q++) {
            int e = t * 8 + q;
            int o = e & 31, k = e >> 5;
            float s = g3[o] * rsqrtf(v3[o] + EPS);
            ws[OFF_W3T + e] = W3[o * 64 + k] * s;
        }
    } else {
        if (t < 64) {
            float s = g2[t] * rsqrtf(v2[t] + EPS);
            ws[OFF_C2 + t] = b2[t] * s + be2[t] - m2[t] * s;
        } else if (t < 96) {
            int o = t - 64;
            float s = g3[o] * rsqrtf(v3[o] + EPS);
            ws[OFF_C3 + o] = b3[o] * s + be3[o] - m3[o] * s;
        } else if (t >= 128) {
            int w = (t >> 6) - 2, l = t & 63;
            if (w < BB) {
                int s = 0;
                #pragma unroll
                for (int q = 0; q < 8; q++) s += (masks[w * NN2 + q * 64 + l] != 0) ? 1 : 0;
                #pragma unroll
                for (int off = 1; off < 64; off <<= 1) s += __shfl_xor(s, off);
                if (l == 0) nvalid[w] = s;
            }
        }
    }
}

// ---------------- per-tile L2+L3+W4-partial (wave-split o-dimension) -------
// U/V rows read DIRECTLY from global (8-way replicated addresses -> one 16B
// request per 8-lane group, L1-resident after first touch; total U/V = 1 MB,
// per-block working set 16 KB). No LDS staging - LDS holds only h2 + partials.
#define H2S 68
__device__ __forceinline__ void tile_eval_g(
    const float* __restrict__ Ur, const float* __restrict__ Vr,  // global rows
    float (*h2)[H2S], float (*part)[65],
    const float* __restrict__ W2t, const float* __restrict__ C2,
    const float* __restrict__ W3t, const float* __restrict__ C3,
    const float* __restrict__ W4, int wq, int lane)
{
    // ---- layer 2: 16 outputs (chunk wq) for this lane's pair ----
    float acc[16];
    const float* c2c = C2 + wq * 16;
    #pragma unroll
    for (int oo = 0; oo < 16; oo++) acc[oo] = c2c[oo];
    #pragma unroll 4
    for (int k = 0; k < 128; k += 4) {
        float4 uk = *(const float4*)&Ur[k];
        float4 vk = *(const float4*)&Vr[k];
        float h0 = fmaxf(uk.x + vk.x, 0.f);
        float h1 = fmaxf(uk.y + vk.y, 0.f);
        float hh2 = fmaxf(uk.z + vk.z, 0.f);
        float h3 = fmaxf(uk.w + vk.w, 0.f);
        const float* w = W2t + k * 64 + wq * 16;   // uniform -> s_load
        #pragma unroll
        for (int oo = 0; oo < 16; oo++) acc[oo] = fmaf(w[oo], h0, acc[oo]);
        #pragma unroll
        for (int oo = 0; oo < 16; oo++) acc[oo] = fmaf(w[64 + oo], h1, acc[oo]);
        #pragma unroll
        for (int oo = 0; oo < 16; oo++) acc[oo] = fmaf(w[128 + oo], hh2, acc[oo]);
        #pragma unroll
        for (int oo = 0; oo < 16; oo++) acc[oo] = fmaf(w[192 + oo], h3, acc[oo]);
    }
    // relu -> LDS h2[pair][o]
    #pragma unroll
    for (int c4 = 0; c4 < 4; c4++) {
        float4 hv;
        hv.x = fmaxf(acc[c4 * 4 + 0], 0.f);
        hv.y = fmaxf(acc[c4 * 4 + 1], 0.f);
        hv.z = fmaxf(acc[c4 * 4 + 2], 0.f);
        hv.w = fmaxf(acc[c4 * 4 + 3], 0.f);
        *(float4*)&h2[lane][wq * 16 + c4 * 4] = hv;
    }
    __syncthreads();
    // ---- layer 3: 8 outputs (chunk wq) + W4 partial ----
    float a3[8];
    const float* c3c = C3 + wq * 8;
    #pragma unroll
    for (int oo = 0; oo < 8; oo++) a3[oo] = c3c[oo];
    const float* hr = &h2[lane][0];
    #pragma unroll 4
    for (int k = 0; k < 64; k += 4) {
        float4 hk = *(const float4*)&hr[k];
        const float* w3 = W3t + k * 32 + wq * 8;   // uniform -> s_load
        #pragma unroll
        for (int oo = 0; oo < 8; oo++) a3[oo] = fmaf(w3[oo], hk.x, a3[oo]);
        #pragma unroll
        for (int oo = 0; oo < 8; oo++) a3[oo] = fmaf(w3[32 + oo], hk.y, a3[oo]);
        #pragma unroll
        for (int oo = 0; oo < 8; oo++) a3[oo] = fmaf(w3[64 + oo], hk.z, a3[oo]);
        #pragma unroll
        for (int oo = 0; oo < 8; oo++) a3[oo] = fmaf(w3[96 + oo], hk.w, a3[oo]);
    }
    float pt = 0.f;
    #pragma unroll
    for (int oo = 0; oo < 8; oo++)
        pt = fmaf(W4[wq * 8 + oo], fmaxf(a3[oo], 0.f), pt);
    part[wq][lane] = pt;
}

// ---------------- Fused main: paired 8x8 tiles + post, no staging ----------
__global__ __launch_bounds__(256) void mlp_fused(
    const float* __restrict__ U, const float* __restrict__ V,
    const float* __restrict__ nfg,
    const float* __restrict__ W2t, const float* __restrict__ C2,
    const float* __restrict__ W3t, const float* __restrict__ C3,
    const float* __restrict__ W4, const float* __restrict__ b4,
    const int* __restrict__ masks, const int* __restrict__ nvalid,
    float* __restrict__ outA, float* __restrict__ outL)
{
    __shared__ __align__(16) float h2[64][H2S];   // 17.4 KB
    __shared__ float pA[4][65], pB[4][65];        // 2.1 KB  -> ~19.5 KB total

    const int t = threadIdx.x;
    const int b = blockIdx.z;
    // decode upper-triangular tile pair (uniform scalar loop)
    int tp = blockIdx.x, ti = 0;
    while (tp >= NT - ti) { tp -= NT - ti; ti++; }
    const int tj = ti + tp;
    const int i0 = ti * 8, j0 = tj * 8;
    const bool offd = (ti != tj);

    const int wq = __builtin_amdgcn_readfirstlane(t >> 6);
    const int lane = t & 63;
    const int pi = lane >> 3, pj = lane & 7;

    const float* UA = U + (size_t)(b * NN2 + i0 + pi) * 128;
    const float* VA = V + (size_t)(b * NN2 + j0 + pj) * 128;

    // A-tile: rows i0 (U), cols j0 (V)
    tile_eval_g(UA, VA, h2, pA, W2t, C2, W3t, C3, W4, wq, lane);
    __syncthreads();
    if (offd) {
        const float* UB = U + (size_t)(b * NN2 + j0 + pi) * 128;
        const float* VB = V + (size_t)(b * NN2 + i0 + pj) * 128;
        tile_eval_g(UB, VB, h2, pB, W2t, C2, W3t, C3, W4, wq, lane);
        __syncthreads();
    }

    const float b40 = b4[0];
    const int nv = nvalid[b];
    if (t < 64) {
        // A position: (i0+i, j0+j)
        const int i = t >> 3, j = t & 7;
        const int tr = j * 8 + i;
        float Lself = b40 + pA[0][t] + pA[1][t] + pA[2][t] + pA[3][t];
        float Ltr = offd ? (b40 + pB[0][tr] + pB[1][tr] + pB[2][tr] + pB[3][tr])
                         : (b40 + pA[0][tr] + pA[1][tr] + pA[2][tr] + pA[3][tr]);
        const int gi = i0 + i, gj = j0 + j;
        float Ls = (gi == gj) ? -10.0f : 0.5f * (Lself + Ltr);
        const float* nfi = nfg + (size_t)(b * NN2 + gi) * 64;
        const float* nfj = nfg + (size_t)(b * NN2 + gj) * 64;
        float sim = 0.f;
        #pragma unroll
        for (int d = 0; d < 64; d += 4) {
            float4 x = *(const float4*)&nfi[d];
            float4 y = *(const float4*)&nfj[d];
            sim = fmaf(x.x, y.x, sim); sim = fmaf(x.y, y.y, sim);
            sim = fmaf(x.z, y.z, sim); sim = fmaf(x.w, y.w, sim);
        }
        float logit = (Ls + 2.0f * sim) * 2.0f;
        float p = 1.0f / (1.0f + expf(-logit));
        p = (p > 0.6f) ? p * 1.2f : p * 0.8f;
        p = fminf(fmaxf(p, 0.0f), 1.0f);
        bool pm = (masks[b * NN2 + gi] != 0) && (masks[b * NN2 + gj] != 0) && (nv > 1);
        size_t idx = (size_t)(b * NN2 + gi) * NN2 + gj;
        outA[idx] = pm ? p : 0.0f;
        outL[idx] = pm ? logit : 0.0f;
    } else if (offd && t < 128) {
        // B position: (j0+i, i0+j)
        const int p8 = t - 64;
        const int i = p8 >> 3, j = p8 & 7;
        const int tr = j * 8 + i;
        float Lself = b40 + pB[0][p8] + pB[1][p8] + pB[2][p8] + pB[3][p8];
        float Ltr   = b40 + pA[0][tr] + pA[1][tr] + pA[2][tr] + pA[3][tr];
        float Ls = 0.5f * (Lself + Ltr);   // disjoint tile ranges: never diagonal
        const int gi = j0 + i, gj = i0 + j;
        const float* nfi = nfg + (size_t)(b * NN2 + gi) * 64;
        const float* nfj = nfg + (size_t)(b * NN2 + gj) * 64;
        float sim = 0.f;
        #pragma unroll
        for (int d = 0; d < 64; d += 4) {
            float4 x = *(const float4*)&nfi[d];
            float4 y = *(const float4*)&nfj[d];
            sim = fmaf(x.x, y.x, sim); sim = fmaf(x.y, y.y, sim);
            sim = fmaf(x.z, y.z, sim); sim = fmaf(x.w, y.w, sim);
        }
        float logit = (Ls + 2.0f * sim) * 2.0f;
        float p = 1.0f / (1.0f + expf(-logit));
        p = (p > 0.6f) ? p * 1.2f : p * 0.8f;
        p = fminf(fmaxf(p, 0.0f), 1.0f);
        bool pm = (masks[b * NN2 + gi] != 0) && (masks[b * NN2 + gj] != 0) && (nv > 1);
        size_t idx = (size_t)(b * NN2 + gi) * NN2 + gj;
        outA[idx] = pm ? p : 0.0f;
        outL[idx] = pm ? logit : 0.0f;
    }
}

// ---------------- launch ----------------
extern "C" void kernel_launch(void* const* d_in, const int* in_sizes, int n_in,
                              void* d_out, int out_size, void* d_ws, size_t ws_size,
                              hipStream_t stream)
{
    const float* feat = (const float*)d_in[0];
    const int*   masks = (const int*)d_in[1];
    const float* W1 = (const float*)d_in[2];
    const float* b1 = (const float*)d_in[3];
    const float* W2 = (const float*)d_in[4];
    const float* b2 = (const float*)d_in[5];
    const float* W3 = (const float*)d_in[6];
    const float* b3 = (const float*)d_in[7];
    const float* W4 = (const float*)d_in[8];
    const float* b4 = (const float*)d_in[9];
    const float* g1 = (const float*)d_in[10];
    const float* be1 = (const float*)d_in[11];
    const float* m1 = (const float*)d_in[12];
    const float* v1 = (const float*)d_in[13];
    const float* g2 = (const float*)d_in[14];
    const float* be2 = (const float*)d_in[15];
    const float* m2 = (const float*)d_in[16];
    const float* v2 = (const float*)d_in[17];
    const float* g3 = (const float*)d_in[18];
    const float* be3 = (const float*)d_in[19];
    const float* m3 = (const float*)d_in[20];
    const float* v3 = (const float*)d_in[21];

    float* ws = (float*)d_ws;
    float* W2t = ws + OFF_W2T;
    float* c2  = ws + OFF_C2;
    float* W3t = ws + OFF_W3T;
    float* c3  = ws + OFF_C3;
    int*   nvalid = (int*)(ws + OFF_NVALID);
    float* Up  = ws + OFF_U;
    float* Vp  = ws + OFF_V;
    float* nfp = ws + OFF_NF;

    float* outA = (float*)d_out;
    float* outL = outA + (size_t)BB * NN2 * NN2;

    prep_all<<<138, 256, 0, stream>>>(feat, masks, W1, b1, W2, b2, W3, b3,
                                      g1, be1, m1, v1, g2, be2, m2, v2,
                                      g3, be3, m3, v3, ws, nvalid);
    dim3 grid(TP, 1, BB);
    mlp_fused<<<grid, 256, 0, stream>>>(Up, Vp, nfp, W2t, c2, W3t, c3, W4, b4,
                                        masks, nvalid, outA, outL);
}

// Round 16
// 226.599 us; speedup vs baseline: 1.3103x; 1.3103x over previous
//
#include <hip/hip_runtime.h>
#include <math.h>

// Problem constants (reference: B=2, N=512, D=64)
#define BB 2
#define NN2 512
#define EPS 1e-5f
#define NT 64      // 512/8 pair-tiles per dim
#define TP 2080    // NT*(NT+1)/2 upper-triangular tile pairs

// ---------------- workspace layout (float offsets) ----------------
#define OFF_W2T    0        // [128][64]  s2-folded W2 transposed -> [k][o]
#define OFF_C2     8192     // [64]
#define OFF_W3T    8256     // [64][32]   s3-folded W3 transposed -> [k][o]
#define OFF_C3     10304    // [32]
#define OFF_NVALID 10336    // [B] ints (16-float pad)
#define OFF_U      10352    // [B*N][128]
#define OFF_V      141424   // [B*N][128]
#define OFF_NF     272496   // [B*N][64]

// ---------------- P1: everything precomputable, one kernel ----------------
__global__ __launch_bounds__(256) void prep_all(
    const float* __restrict__ feat, const int* __restrict__ masks,
    const float* __restrict__ W1, const float* __restrict__ b1,
    const float* __restrict__ W2, const float* __restrict__ b2,
    const float* __restrict__ W3, const float* __restrict__ b3,
    const float* __restrict__ g1, const float* __restrict__ be1,
    const float* __restrict__ m1, const float* __restrict__ v1,
    const float* __restrict__ g2, const float* __restrict__ be2,
    const float* __restrict__ m2, const float* __restrict__ v2,
    const float* __restrict__ g3, const float* __restrict__ be3,
    const float* __restrict__ m3, const float* __restrict__ v3,
    float* __restrict__ ws, int* __restrict__ nvalid)
{
    const int blk = blockIdx.x, t = threadIdx.x;
    if (blk < 128) {
        __shared__ float F[8][64];
        const int nb = blk * 8;
        if (t < 128) {
            int r = t >> 4, c = (t & 15) * 4;
            *(float4*)&F[r][c] = *(const float4*)&feat[(nb + r) * 64 + c];
        }
        __syncthreads();
        if (t < 128) {
            int g = t >> 4, c0 = t & 15;
            float x0 = F[g][c0],      x1 = F[g][c0 + 16];
            float x2 = F[g][c0 + 32], x3 = F[g][c0 + 48];
            float ss = x0*x0 + x1*x1 + x2*x2 + x3*x3;
            ss += __shfl_xor(ss, 1);
            ss += __shfl_xor(ss, 2);
            ss += __shfl_xor(ss, 4);
            ss += __shfl_xor(ss, 8);
            float inv = 1.0f / fmaxf(sqrtf(ss), 1e-12f);
            float* nfp = ws + OFF_NF + (size_t)(nb + g) * 64 + c0;
            nfp[0]  = x0 * inv; nfp[16] = x1 * inv;
            nfp[32] = x2 * inv; nfp[48] = x3 * inv;
        }
        const int g = t >> 7, o = t & 127;
        const float s1 = g1[o] * rsqrtf(v1[o] + EPS);
        const float vb = s1 * b1[o] + be1[o] - m1[o] * s1;
        float aU[4] = {0.f,0.f,0.f,0.f}, aV[4] = {0.f,0.f,0.f,0.f};
        const float* w1r = &W1[o * 128];
        #pragma unroll 4
        for (int dq = 0; dq < 16; dq++) {
            float4 wa = *(const float4*)&w1r[dq * 4];
            float4 wb = *(const float4*)&w1r[64 + dq * 4];
            #pragma unroll
            for (int n = 0; n < 4; n++) {
                float4 fv = *(const float4*)&F[g * 4 + n][dq * 4];
                aU[n] = fmaf(fv.x, wa.x, aU[n]); aV[n] = fmaf(fv.x, wb.x, aV[n]);
                aU[n] = fmaf(fv.y, wa.y, aU[n]); aV[n] = fmaf(fv.y, wb.y, aV[n]);
                aU[n] = fmaf(fv.z, wa.z, aU[n]); aV[n] = fmaf(fv.z, wb.z, aV[n]);
                aU[n] = fmaf(fv.w, wa.w, aU[n]); aV[n] = fmaf(fv.w, wb.w, aV[n]);
            }
        }
        float* Up = ws + OFF_U;
        float* Vp = ws + OFF_V;
        #pragma unroll
        for (int n = 0; n < 4; n++) {
            Up[(size_t)(nb + g * 4 + n) * 128 + o] = aU[n] * s1;
            Vp[(size_t)(nb + g * 4 + n) * 128 + o] = aV[n] * s1 + vb;
        }
    } else if (blk < 136) {
        int e0 = (blk - 128) * 1024 + t * 4;
        #pragma unroll
        for (int q = 0; q < 4; q++) {
            int e = e0 + q;
            int o = e & 63, k = e >> 6;
            float s = g2[o] * rsqrtf(v2[o] + EPS);
            ws[OFF_W2T + e] = W2[o * 128 + k] * s;
        }
    } else if (blk == 136) {
        #pragma unroll
        for (int q = 0; q < 8; q++) {
            int e = t * 8 + q;
            int o = e & 31, k = e >> 5;
            float s = g3[o] * rsqrtf(v3[o] + EPS);
            ws[OFF_W3T + e] = W3[o * 64 + k] * s;
        }
    } else {
        if (t < 64) {
            float s = g2[t] * rsqrtf(v2[t] + EPS);
            ws[OFF_C2 + t] = b2[t] * s + be2[t] - m2[t] * s;
        } else if (t < 96) {
            int o = t - 64;
            float s = g3[o] * rsqrtf(v3[o] + EPS);
            ws[OFF_C3 + o] = b3[o] * s + be3[o] - m3[o] * s;
        } else if (t >= 128) {
            int w = (t >> 6) - 2, l = t & 63;
            if (w < BB) {
                int s = 0;
                #pragma unroll
                for (int q = 0; q < 8; q++) s += (masks[w * NN2 + q * 64 + l] != 0) ? 1 : 0;
                #pragma unroll
                for (int off = 1; off < 64; off <<= 1) s += __shfl_xor(s, off);
                if (l == 0) nvalid[w] = s;
            }
        }
    }
}

#define UVS 132
#define H2S 68

// ---------------- layer-3 + W4 partial for one h2 row ----------------------
__device__ __forceinline__ float l3_eval(
    const float* hr,
    const float* __restrict__ W3t, const float* __restrict__ C3,
    const float* __restrict__ W4, int wq)
{
    float a3[8];
    const float* c3c = C3 + wq * 8;
    #pragma unroll
    for (int oo = 0; oo < 8; oo++) a3[oo] = c3c[oo];
    #pragma unroll 4
    for (int k = 0; k < 64; k += 4) {
        float4 hk = *(const float4*)&hr[k];
        const float* w3 = W3t + k * 32 + wq * 8;   // uniform -> s_load
        #pragma unroll
        for (int oo = 0; oo < 8; oo++) a3[oo] = fmaf(w3[oo], hk.x, a3[oo]);
        #pragma unroll
        for (int oo = 0; oo < 8; oo++) a3[oo] = fmaf(w3[32 + oo], hk.y, a3[oo]);
        #pragma unroll
        for (int oo = 0; oo < 8; oo++) a3[oo] = fmaf(w3[64 + oo], hk.z, a3[oo]);
        #pragma unroll
        for (int oo = 0; oo < 8; oo++) a3[oo] = fmaf(w3[96 + oo], hk.w, a3[oo]);
    }
    float pt = 0.f;
    #pragma unroll
    for (int oo = 0; oo < 8; oo++)
        pt = fmaf(W4[wq * 8 + oo], fmaxf(a3[oo], 0.f), pt);
    return pt;
}

// ---------------- Fused main: merged A+B k-loop, wave-split o-dim ----------
// Change vs R12: the A and B tiles' layer-2 run in ONE k-loop sharing the
// weight s_loads (half the s_load stream) with two independent accumulator
// chains (2x ILP). accA[16]+accB[16] = 32 live accs (spill tripwire:
// WRITE_SIZE must stay ~4096 KB). Diagonal tiles compute B redundantly
// (~3% waste) to keep the MLP phase branchless.
__global__ __launch_bounds__(256) void mlp_fused(
    const float* __restrict__ U, const float* __restrict__ V,
    const float* __restrict__ nfg,
    const float* __restrict__ W2t, const float* __restrict__ C2,
    const float* __restrict__ W3t, const float* __restrict__ C3,
    const float* __restrict__ W4, const float* __restrict__ b4,
    const int* __restrict__ masks, const int* __restrict__ nvalid,
    float* __restrict__ outA, float* __restrict__ outL)
{
    __shared__ __align__(16) float lds[4 * 8 * UVS + 64 * H2S + 2 * 4 * 65];
    float (*Ui)[UVS] = (float(*)[UVS])(lds);
    float (*Vi)[UVS] = (float(*)[UVS])(lds + 8 * UVS);
    float (*Uj)[UVS] = (float(*)[UVS])(lds + 2 * 8 * UVS);
    float (*Vj)[UVS] = (float(*)[UVS])(lds + 3 * 8 * UVS);
    float (*h2)[H2S] = (float(*)[H2S])(lds + 4 * 8 * UVS);
    // overlay on h2 (dead after last l3_eval): nf tiles
    float (*nfI)[H2S] = (float(*)[H2S])(lds + 4 * 8 * UVS);
    float (*nfJ)[H2S] = (float(*)[H2S])(lds + 4 * 8 * UVS + 8 * H2S);
    float (*pA)[65] = (float(*)[65])(lds + 4 * 8 * UVS + 64 * H2S);
    float (*pB)[65] = (float(*)[65])(lds + 4 * 8 * UVS + 64 * H2S + 4 * 65);
    __shared__ int mI[8], mJ[8];

    const int t = threadIdx.x;
    const int b = blockIdx.z;
    // decode upper-triangular tile pair (uniform scalar loop)
    int tp = blockIdx.x, ti = 0;
    while (tp >= NT - ti) { tp -= NT - ti; ti++; }
    const int tj = ti + tp;
    const int i0 = ti * 8, j0 = tj * 8;
    const bool offd = (ti != tj);

    const int wq = __builtin_amdgcn_readfirstlane(t >> 6);
    const int lane = t & 63;
    const int pi = lane >> 3, pj = lane & 7;

    // wave wq stages tile wq: {Ui, Vi, Uj, Vj}
    {
        const int r = lane >> 3, c = (lane & 7) * 16;
        const int row = (wq & 2) ? j0 + r : i0 + r;
        const float* base = (wq & 1) ? V : U;
        const float* src = &base[(size_t)(b * NN2 + row) * 128 + c];
        float* dst = (wq == 0) ? &Ui[r][c] : (wq == 1) ? &Vi[r][c]
                   : (wq == 2) ? &Uj[r][c] : &Vj[r][c];
        #pragma unroll
        for (int e = 0; e < 4; e++)
            *(float4*)(dst + 4 * e) = *(const float4*)(src + 4 * e);
    }
    if (t < 8) mI[t] = masks[b * NN2 + i0 + t];
    else if (t < 16) mJ[t - 8] = masks[b * NN2 + j0 + (t - 8)];
    __syncthreads();

    // ---- merged layer-2: A-tile (Ui,Vj) and B-tile (Uj,Vi), shared weights
    float accA[16], accB[16];
    {
        const float* c2c = C2 + wq * 16;
        #pragma unroll
        for (int oo = 0; oo < 16; oo++) { accA[oo] = c2c[oo]; accB[oo] = c2c[oo]; }
        const float* UrA = &Ui[pi][0];
        const float* VrA = &Vj[pj][0];
        const float* UrB = &Uj[pi][0];
        const float* VrB = &Vi[pj][0];
        #pragma unroll 2
        for (int k = 0; k < 128; k += 4) {
            float4 ukA = *(const float4*)&UrA[k];
            float4 vkA = *(const float4*)&VrA[k];
            float4 ukB = *(const float4*)&UrB[k];
            float4 vkB = *(const float4*)&VrB[k];
            float hA0 = fmaxf(ukA.x + vkA.x, 0.f);
            float hA1 = fmaxf(ukA.y + vkA.y, 0.f);
            float hA2 = fmaxf(ukA.z + vkA.z, 0.f);
            float hA3 = fmaxf(ukA.w + vkA.w, 0.f);
            float hB0 = fmaxf(ukB.x + vkB.x, 0.f);
            float hB1 = fmaxf(ukB.y + vkB.y, 0.f);
            float hB2 = fmaxf(ukB.z + vkB.z, 0.f);
            float hB3 = fmaxf(ukB.w + vkB.w, 0.f);
            const float* w = W2t + k * 64 + wq * 16;   // uniform -> s_load (once for A+B)
            #pragma unroll
            for (int oo = 0; oo < 16; oo++) {
                float wv = w[oo];
                accA[oo] = fmaf(wv, hA0, accA[oo]);
                accB[oo] = fmaf(wv, hB0, accB[oo]);
            }
            #pragma unroll
            for (int oo = 0; oo < 16; oo++) {
                float wv = w[64 + oo];
                accA[oo] = fmaf(wv, hA1, accA[oo]);
                accB[oo] = fmaf(wv, hB1, accB[oo]);
            }
            #pragma unroll
            for (int oo = 0; oo < 16; oo++) {
                float wv = w[128 + oo];
                accA[oo] = fmaf(wv, hA2, accA[oo]);
                accB[oo] = fmaf(wv, hB2, accB[oo]);
            }
            #pragma unroll
            for (int oo = 0; oo < 16; oo++) {
                float wv = w[192 + oo];
                accA[oo] = fmaf(wv, hA3, accA[oo]);
                accB[oo] = fmaf(wv, hB3, accB[oo]);
            }
        }
    }
    // ---- layer-3 for A ----
    #pragma unroll
    for (int c4 = 0; c4 < 4; c4++) {
        float4 hv;
        hv.x = fmaxf(accA[c4 * 4 + 0], 0.f);
        hv.y = fmaxf(accA[c4 * 4 + 1], 0.f);
        hv.z = fmaxf(accA[c4 * 4 + 2], 0.f);
        hv.w = fmaxf(accA[c4 * 4 + 3], 0.f);
        *(float4*)&h2[lane][wq * 16 + c4 * 4] = hv;
    }
    __syncthreads();
    pA[wq][lane] = l3_eval(&h2[lane][0], W3t, C3, W4, wq);
    __syncthreads();                       // h2 reads done; pA visible later
    // ---- layer-3 for B (reuse h2) ----
    #pragma unroll
    for (int c4 = 0; c4 < 4; c4++) {
        float4 hv;
        hv.x = fmaxf(accB[c4 * 4 + 0], 0.f);
        hv.y = fmaxf(accB[c4 * 4 + 1], 0.f);
        hv.z = fmaxf(accB[c4 * 4 + 2], 0.f);
        hv.w = fmaxf(accB[c4 * 4 + 3], 0.f);
        *(float4*)&h2[lane][wq * 16 + c4 * 4] = hv;
    }
    __syncthreads();
    pB[wq][lane] = l3_eval(&h2[lane][0], W3t, C3, W4, wq);
    __syncthreads();                       // pB visible; h2 free for overlay

    // nf tiles into the h2 overlay
    if (t < 64) {
        int r = t >> 3, c = (t & 7) * 8;
        const float* src = &nfg[(size_t)(b * NN2 + i0 + r) * 64 + c];
        *(float4*)&nfI[r][c]     = *(const float4*)src;
        *(float4*)&nfI[r][c + 4] = *(const float4*)(src + 4);
    } else if (t < 128) {
        int tt = t - 64;
        int r = tt >> 3, c = (tt & 7) * 8;
        const float* src = &nfg[(size_t)(b * NN2 + j0 + r) * 64 + c];
        *(float4*)&nfJ[r][c]     = *(const float4*)src;
        *(float4*)&nfJ[r][c + 4] = *(const float4*)(src + 4);
    }
    __syncthreads();

    const float b40 = b4[0];
    const int nv = nvalid[b];
    if (t < 64) {
        // A position: (i0+i, j0+j)
        const int i = t >> 3, j = t & 7;
        const int tr = j * 8 + i;
        float Lself = b40 + pA[0][t] + pA[1][t] + pA[2][t] + pA[3][t];
        float Ltr = offd ? (b40 + pB[0][tr] + pB[1][tr] + pB[2][tr] + pB[3][tr])
                         : (b40 + pA[0][tr] + pA[1][tr] + pA[2][tr] + pA[3][tr]);
        const int gi = i0 + i, gj = j0 + j;
        float Ls = (gi == gj) ? -10.0f : 0.5f * (Lself + Ltr);
        float sim = 0.f;
        #pragma unroll
        for (int d = 0; d < 64; d += 4) {
            float4 x = *(const float4*)&nfI[i][d];
            float4 y = *(const float4*)&nfJ[j][d];
            sim = fmaf(x.x, y.x, sim); sim = fmaf(x.y, y.y, sim);
            sim = fmaf(x.z, y.z, sim); sim = fmaf(x.w, y.w, sim);
        }
        float logit = (Ls + 2.0f * sim) * 2.0f;
        float p = 1.0f / (1.0f + expf(-logit));
        p = (p > 0.6f) ? p * 1.2f : p * 0.8f;
        p = fminf(fmaxf(p, 0.0f), 1.0f);
        bool pm = (mI[i] != 0) && (mJ[j] != 0) && (nv > 1);
        size_t idx = (size_t)(b * NN2 + gi) * NN2 + gj;
        outA[idx] = pm ? p : 0.0f;
        outL[idx] = pm ? logit : 0.0f;
    } else if (offd && t < 128) {
        // B position: (j0+i, i0+j)
        const int p8 = t - 64;
        const int i = p8 >> 3, j = p8 & 7;
        const int tr = j * 8 + i;
        float Lself = b40 + pB[0][p8] + pB[1][p8] + pB[2][p8] + pB[3][p8];
        float Ltr   = b40 + pA[0][tr] + pA[1][tr] + pA[2][tr] + pA[3][tr];
        float Ls = 0.5f * (Lself + Ltr);   // disjoint tile ranges: never diagonal
        float sim = 0.f;
        #pragma unroll
        for (int d = 0; d < 64; d += 4) {
            float4 x = *(const float4*)&nfJ[i][d];
            float4 y = *(const float4*)&nfI[j][d];
            sim = fmaf(x.x, y.x, sim); sim = fmaf(x.y, y.y, sim);
            sim = fmaf(x.z, y.z, sim); sim = fmaf(x.w, y.w, sim);
        }
        float logit = (Ls + 2.0f * sim) * 2.0f;
        float p = 1.0f / (1.0f + expf(-logit));
        p = (p > 0.6f) ? p * 1.2f : p * 0.8f;
        p = fminf(fmaxf(p, 0.0f), 1.0f);
        bool pm = (mJ[i] != 0) && (mI[j] != 0) && (nv > 1);
        size_t idx = (size_t)(b * NN2 + j0 + i) * NN2 + (i0 + j);
        outA[idx] = pm ? p : 0.0f;
        outL[idx] = pm ? logit : 0.0f;
    }
}

// ---------------- launch ----------------
extern "C" void kernel_launch(void* const* d_in, const int* in_sizes, int n_in,
                              void* d_out, int out_size, void* d_ws, size_t ws_size,
                              hipStream_t stream)
{
    const float* feat = (const float*)d_in[0];
    const int*   masks = (const int*)d_in[1];
    const float* W1 = (const float*)d_in[2];
    const float* b1 = (const float*)d_in[3];
    const float* W2 = (const float*)d_in[4];
    const float* b2 = (const float*)d_in[5];
    const float* W3 = (const float*)d_in[6];
    const float* b3 = (const float*)d_in[7];
    const float* W4 = (const float*)d_in[8];
    const float* b4 = (const float*)d_in[9];
    const float* g1 = (const float*)d_in[10];
    const float* be1 = (const float*)d_in[11];
    const float* m1 = (const float*)d_in[12];
    const float* v1 = (const float*)d_in[13];
    const float* g2 = (const float*)d_in[14];
    const float* be2 = (const float*)d_in[15];
    const float* m2 = (const float*)d_in[16];
    const float* v2 = (const float*)d_in[17];
    const float* g3 = (const float*)d_in[18];
    const float* be3 = (const float*)d_in[19];
    const float* m3 = (const float*)d_in[20];
    const float* v3 = (const float*)d_in[21];

    float* ws = (float*)d_ws;
    float* W2t = ws + OFF_W2T;
    float* c2  = ws + OFF_C2;
    float* W3t = ws + OFF_W3T;
    float* c3  = ws + OFF_C3;
    int*   nvalid = (int*)(ws + OFF_NVALID);
    float* Up  = ws + OFF_U;
    float* Vp  = ws + OFF_V;
    float* nfp = ws + OFF_NF;

    float* outA = (float*)d_out;
    float* outL = outA + (size_t)BB * NN2 * NN2;

    prep_all<<<138, 256, 0, stream>>>(feat, masks, W1, b1, W2, b2, W3, b3,
                                      g1, be1, m1, v1, g2, be2, m2, v2,
                                      g3, be3, m3, v3, ws, nvalid);
    dim3 grid(TP, 1, BB);
    mlp_fused<<<grid, 256, 0, stream>>>(Up, Vp, nfp, W2t, c2, W3t, c3, W4, b4,
                                        masks, nvalid, outA, outL);
}